// Round 3
// baseline (235.816 us; speedup 1.0000x reference)
//
#include <hip/hip_runtime.h>

// LIF neuron forward: T=8 timesteps, x shape [T*B, C, H, W] = [256,128,32,32] f32.
// Recurrence per spatial element (independent across B,C,H,W):
//   mem = beta*mem + (1-beta)*x_t ; spike = (mem >= 0.3*Vth)*Vth ;
//   mem -= spike ; out_t = spike/0.05
//
// History:
//  R1: 1 float4/thread one-shot: 87 us, ~3.0 TB/s CU-side. Pipes idle.
//  R3: nt stores: 100 us (reverted). R4/R5: asm pins defeated/no effect.
//  R6: grid-stride x4, occupancy 62->31%: 94 us. Occupancy-insensitive.
//  R7: 2 contiguous cols/thread: 82 us. R8: K_COLS=8 interleaved, 32 KB
//      block bursts: 79.5 us. Burst length was the only lever that moved.
//  R9: whole-kernel read burst via 16 SEPARATE asm pins: defeated
//      (VGPR=40 proves loads not simultaneously live). 84-90 us.
//  R10: ONE 16-operand "+v" asm pin: ALSO defeated (VGPR still 40 --
//      physically impossible if 16 float4 were live; LLVM coalesced the
//      tied operands / rescheduled around the empty asm). 82-85 us.
//      Meanwhile occupancy 17%->45% across R8->R10 moved nothing: wave
//      count is not the limiter; the per-wave schedule is.
//  R11 (this): give up on C++-level hints -- emit the read burst in
//      inline asm. 16 x volatile global_load_dwordx4 (SGPR base + 32-bit
//      voffset; whole array is 128 MB so offsets fit). Volatile asms keep
//      program order -> guaranteed 16-load burst, 16 KB reads in flight
//      per wave. Then ONE explicit s_waitcnt vmcnt(0) + sched_barrier(0)
//      (rule #18: stops hipcc hoisting dependent VALU above an inline-asm
//      wait), then compute, then plain C++ stores (store-data regs never
//      redefined -> no waits on stores; they drain behind the next waves'
//      read bursts). Diagnosis being tested: per-timestep register reuse
//      forced vmcnt(0) waits that drain slow stores before each timestep's
//      loads -> time-averaged read MLP ~2.5 KB/CU (Little's law from
//      2.75 B/cy/CU @ ~800cy) -> reads latency-bound at half copy BW.
//      Verification: VGPR_Count must be ~90+ (16 float4 live across the
//      wait). If VGPR~90 and still ~80 us -> theory falsified, pattern is
//      at a systemic RW-mix limit -> roofline.
//
// Bit-exactness notes (decisions flip 0<->20, zero flips allowed):
//  - beta = f32(exp(f32(-0.05))) = 0x1.E7078Cp-1 (correctly rounded; verified
//    absmax 0.0 in R1..R10).
//  - mem update uses __fmul_rn/__fadd_rn to forbid FMA contraction (numpy
//    evaluates beta*mem and (1-beta)*xt as separate rn-multiplies + rn-add).
//  - (1.0f - beta) exact; Vth clamp round-trips to 1.0f; vth/0.05f == 20.0f.
//  - asm global_load_dwordx4 returns identical bits to a C++ load; compute
//    chain untouched.

#define T_STEPS 8
#define S_ELEMS (32 * 128 * 32 * 32)   // per-timestep elements = 4,194,304
#define S4 (S_ELEMS / 4)               // float4 per timestep = 1,048,576
#define BLOCK 256
#define K_COLS 2                       // interleaved columns per thread
#define GRID (S4 / (BLOCK * K_COLS))   // 2048 blocks = 8 blocks/CU

typedef float f32x4 __attribute__((ext_vector_type(4)));

__global__ __launch_bounds__(BLOCK) void lif_fwd_kernel(
    const f32x4* __restrict__ x, const float* __restrict__ vth_ptr,
    f32x4* __restrict__ out) {
  // Block covers BLOCK*K_COLS consecutive float4 per plane; thread handles
  // columns base + k*BLOCK so every load/store inst is a coalesced 1-KB
  // wave access.
  const int base = blockIdx.x * (BLOCK * K_COLS) + threadIdx.x;

  // Vth clamp (no-grad): relu(Vth - 5e-4) + 5e-4, all f32 rn. (scalar path)
  const float vth_raw = vth_ptr[0];
  const float vth = __fadd_rn(fmaxf(__fsub_rn(vth_raw, 0.0005f), 0.0f), 0.0005f);
  const float thr = __fmul_rn(0.3f, vth);      // ALPHA * Vth
  const float outval = __fdiv_rn(vth, 0.05f);  // Vth / DELTA_T (== 20.0f)

  const float beta = 0x1.E7078Cp-1f;        // f32(exp(f32(-0.05)))
  const float omb = __fsub_rn(1.0f, beta);  // exact

  // === Whole-kernel read burst, enforced at ISA level. ===
  // 16 volatile global_load_dwordx4: program order guaranteed among
  // volatile asms; nothing can interleave waits or stores into the burst.
  // Addressing: uniform SGPR base (kernel arg) + per-lane 32-bit byte
  // voffset (max offset = 8*16 MiB = 128 MiB, fits u32).
  f32x4 xv[T_STEPS][K_COLS];
  const unsigned b16 = (unsigned)base * 16u;
#pragma unroll
  for (int t = 0; t < T_STEPS; ++t) {
#pragma unroll
    for (int k = 0; k < K_COLS; ++k) {
      const unsigned off =
          b16 + (unsigned)(k * BLOCK) * 16u + (unsigned)t * (unsigned)(S4 * 16);
      asm volatile("global_load_dwordx4 %0, %1, %2"
                   : "=v"(xv[t][k])
                   : "v"(off), "s"(x));
    }
  }

  // One drain of the read burst, then a scheduling fence so the dependent
  // VALU below cannot be hoisted above the wait (guide rule #18).
  asm volatile("s_waitcnt vmcnt(0)" ::: "memory");
  __builtin_amdgcn_sched_barrier(0);

  float m[K_COLS * 4];
#pragma unroll
  for (int j = 0; j < K_COLS * 4; ++j) m[j] = 0.0f;

#pragma unroll
  for (int t = 0; t < T_STEPS; ++t) {
#pragma unroll
    for (int k = 0; k < K_COLS; ++k) {
#pragma unroll
      for (int c = 0; c < 4; ++c) {
        const float mm =
            __fadd_rn(__fmul_rn(beta, m[k * 4 + c]), __fmul_rn(omb, xv[t][k][c]));
        const bool s = (mm >= thr);
        // Write the spike into the xv register; the store below is its
        // last use, so no store-data reg is ever redefined -> the compiler
        // never needs an s_waitcnt on any store.
        xv[t][k][c] = s ? outval : 0.0f;
        m[k * 4 + c] = s ? __fsub_rn(mm, vth) : mm;
      }
      out[base + k * BLOCK + (size_t)t * S4] = xv[t][k];
    }
  }
}

extern "C" void kernel_launch(void* const* d_in, const int* in_sizes, int n_in,
                              void* d_out, int out_size, void* d_ws,
                              size_t ws_size, hipStream_t stream) {
  const f32x4* x = (const f32x4*)d_in[0];
  const float* vth = (const float*)d_in[1];
  f32x4* out = (f32x4*)d_out;
  lif_fwd_kernel<<<GRID, BLOCK, 0, stream>>>(x, vth, out);
}

// Round 4
// 234.671 us; speedup vs baseline: 1.0049x; 1.0049x over previous
//
#include <hip/hip_runtime.h>

// LIF neuron forward: T=8 timesteps, x shape [T*B, C, H, W] = [256,128,32,32] f32.
// Recurrence per spatial element (independent across B,C,H,W):
//   mem = beta*mem + (1-beta)*x_t ; spike = (mem >= 0.3*Vth)*Vth ;
//   mem -= spike ; out_t = spike/0.05
//
// History:
//  R1: 1 float4/thread one-shot: 87 us, ~3.0 TB/s CU-side. Pipes idle.
//  R3: nt stores: 100 us (reverted). R4/R5: asm pins defeated/no effect.
//  R6: grid-stride x4, occupancy 62->31%: 94 us. Occupancy-insensitive.
//  R7: 2 contiguous cols/thread: 82 us. R8: K_COLS=8 interleaved, 32 KB
//      block bursts: 79.5 us. Burst length the only lever that moved.
//  R9: whole-kernel read burst via 16 SEPARATE asm pins: defeated
//      (VGPR=40 proves loads not simultaneously live). 84-90 us.
//  R10: ONE 16-operand "+v" asm pin: counters again 40/48, ~83 us.
//  R11: 16 volatile inline-asm global_load_dwordx4 + explicit vmcnt(0) +
//      sched_barrier(0). Counters came back BIT-IDENTICAL to R9/R10
//      (VGPR=40/SGPR=48/dur~82). That is PHYSICALLY IMPOSSIBLE for this
//      source: all 16 asm outputs are live across the volatile waitcnt
//      (>=64 VGPRs; no scratch -- FETCH_SIZE unchanged, LDS=0). Leading
//      hypothesis: the bench ran a STALE BINARY for R10/R11.
//  R12 (this): identical structure to R11 plus unforgeable freshness
//      signatures: kernel renamed lif_fwd_r12 (Kernel_Name must change),
//      256 B LDS touched once (LDS_Block_Size must read 256), and the
//      VGPR>=72 liveness argument. If signatures appear and perf jumps:
//      read-MLP theory confirmed. If signatures appear and perf stays
//      ~80 us: theory falsified (and NOT roofline -- m13 float4 copy does
//      6.29 TB/s on the same 1:1 RW mix). If signatures absent: harness
//      is benching stale artifacts; R9-R11 conclusions void.
//
// Bit-exactness notes (decisions flip 0<->20, zero flips allowed):
//  - beta = f32(exp(f32(-0.05))) = 0x1.E7078Cp-1 (correctly rounded; verified
//    absmax 0.0 in R1..R11).
//  - mem update uses __fmul_rn/__fadd_rn to forbid FMA contraction (numpy
//    evaluates beta*mem and (1-beta)*xt as separate rn-multiplies + rn-add).
//  - (1.0f - beta) exact; Vth clamp round-trips to 1.0f; vth/0.05f == 20.0f.
//  - asm global_load_dwordx4 returns identical bits to a C++ load; compute
//    chain untouched.

#define T_STEPS 8
#define S_ELEMS (32 * 128 * 32 * 32)   // per-timestep elements = 4,194,304
#define S4 (S_ELEMS / 4)               // float4 per timestep = 1,048,576
#define BLOCK 256
#define K_COLS 2                       // interleaved columns per thread
#define GRID (S4 / (BLOCK * K_COLS))   // 2048 blocks = 8 blocks/CU

typedef float f32x4 __attribute__((ext_vector_type(4)));

__global__ __launch_bounds__(BLOCK) void lif_fwd_r12(
    const f32x4* __restrict__ x, const float* __restrict__ vth_ptr,
    f32x4* __restrict__ out) {
  // Freshness signature #2: 256 B LDS, written once, never read.
  // LDS_Block_Size in the counter CSV must read 256 if this binary runs.
  __shared__ float freshness_sig[64];
  if (threadIdx.x == 0) {
    ((volatile float*)freshness_sig)[0] = 0.0f;
  }

  // Block covers BLOCK*K_COLS consecutive float4 per plane; thread handles
  // columns base + k*BLOCK so every load/store inst is a coalesced 1-KB
  // wave access.
  const int base = blockIdx.x * (BLOCK * K_COLS) + threadIdx.x;

  // Vth clamp (no-grad): relu(Vth - 5e-4) + 5e-4, all f32 rn. (scalar path)
  const float vth_raw = vth_ptr[0];
  const float vth = __fadd_rn(fmaxf(__fsub_rn(vth_raw, 0.0005f), 0.0f), 0.0005f);
  const float thr = __fmul_rn(0.3f, vth);      // ALPHA * Vth
  const float outval = __fdiv_rn(vth, 0.05f);  // Vth / DELTA_T (== 20.0f)

  const float beta = 0x1.E7078Cp-1f;        // f32(exp(f32(-0.05)))
  const float omb = __fsub_rn(1.0f, beta);  // exact

  // === Whole-kernel read burst, enforced at ISA level. ===
  // 16 volatile global_load_dwordx4: program order guaranteed among
  // volatile asms; nothing can interleave waits or stores into the burst.
  // Addressing: uniform SGPR base (kernel arg) + per-lane 32-bit byte
  // voffset (max offset ~129 MiB, fits u32 / positive s32).
  f32x4 xv[T_STEPS][K_COLS];
  const unsigned b16 = (unsigned)base * 16u;
#pragma unroll
  for (int t = 0; t < T_STEPS; ++t) {
#pragma unroll
    for (int k = 0; k < K_COLS; ++k) {
      const unsigned off =
          b16 + (unsigned)(k * BLOCK) * 16u + (unsigned)t * (unsigned)(S4 * 16);
      asm volatile("global_load_dwordx4 %0, %1, %2"
                   : "=v"(xv[t][k])
                   : "v"(off), "s"(x));
    }
  }

  // One drain of the read burst, then a scheduling fence so the dependent
  // VALU below cannot be hoisted above the wait (guide rule #18).
  asm volatile("s_waitcnt vmcnt(0)" ::: "memory");
  __builtin_amdgcn_sched_barrier(0);

  float m[K_COLS * 4];
#pragma unroll
  for (int j = 0; j < K_COLS * 4; ++j) m[j] = 0.0f;

#pragma unroll
  for (int t = 0; t < T_STEPS; ++t) {
#pragma unroll
    for (int k = 0; k < K_COLS; ++k) {
#pragma unroll
      for (int c = 0; c < 4; ++c) {
        const float mm =
            __fadd_rn(__fmul_rn(beta, m[k * 4 + c]), __fmul_rn(omb, xv[t][k][c]));
        const bool s = (mm >= thr);
        // Write the spike into the xv register; the store below is its
        // last use, so no store-data reg is ever redefined -> the compiler
        // never needs an s_waitcnt on any store.
        xv[t][k][c] = s ? outval : 0.0f;
        m[k * 4 + c] = s ? __fsub_rn(mm, vth) : mm;
      }
      out[base + k * BLOCK + (size_t)t * S4] = xv[t][k];
    }
  }
}

extern "C" void kernel_launch(void* const* d_in, const int* in_sizes, int n_in,
                              void* d_out, int out_size, void* d_ws,
                              size_t ws_size, hipStream_t stream) {
  const f32x4* x = (const f32x4*)d_in[0];
  const float* vth = (const float*)d_in[1];
  f32x4* out = (f32x4*)d_out;
  lif_fwd_r12<<<GRID, BLOCK, 0, stream>>>(x, vth, out);
}